// Round 3
// baseline (145.786 us; speedup 1.0000x reference)
//
#include <hip/hip_runtime.h>

#define IC 64
#define OC 64
#define NSH 45
#define BATCH 2048
#define PI_F 3.14159265358979323846f
#define WF_FLOATS (NSH * IC * OC)   // 184,320 floats = 737,280 B

// 4B-aligned vector types (hardware allows dword-aligned multi-dword ops)
typedef float f4a4 __attribute__((ext_vector_type(4), aligned(4)));
typedef float f2a8 __attribute__((ext_vector_type(2), aligned(8)));

// ---------------- weight fold: wf[c][i][o] = w[o][i][ls[c]/2] * sqrt(pi/(2l+1))
// 46080 threads, each: 4 scalar gathers (L2-hot 80 KB) + 1 dwordx4 store.
__global__ __launch_bounds__(256) void fold_kernel(const float* __restrict__ w,
                                                   const int* __restrict__ ls,
                                                   float* __restrict__ wf) {
    int t = blockIdx.x * 256 + threadIdx.x;   // [0, 45*64*16)
    if (t >= NSH * IC * 16) return;
    int o4 = t & 15;
    int i  = (t >> 4) & 63;
    int c  = t >> 10;                          // [0, 45)
    int l  = ls[c];
    int l2 = l >> 1;
    float sc = sqrtf(PI_F / (2.0f * (float)l + 1.0f));
    int o0 = o4 * 4;
    f4a4 v;
    v[0] = w[((o0 + 0) * IC + i) * 5 + l2] * sc;
    v[1] = w[((o0 + 1) * IC + i) * 5 + l2] * sc;
    v[2] = w[((o0 + 2) * IC + i) * 5 + l2] * sc;
    v[3] = w[((o0 + 3) * IC + i) * 5 + l2] * sc;
    *(f4a4*)(wf + ((size_t)c * IC + i) * OC + o0) = v;
}

// ---------------- main kernel: no LDS, c-vectorized loads/stores.
// Grid 1536 = 64 bt (32 rows) x 4 ot (16 o) x 6 ct (2 c-quads).
// Block 128 thr = (bq 8) x (og 8) x (cq 2); thread tile 4b x 2o x 4c.
template <bool FOLDED>
__global__ __launch_bounds__(128) void sph_main(const float* __restrict__ x,
                                                const float* __restrict__ w,
                                                const int* __restrict__ ls,
                                                float* __restrict__ out) {
    // bijective XCD swizzle (1536 % 8 == 0): each XCD owns 8 consecutive bt
    // -> all 24 (ot,ct) blocks of a bt share that XCD's L2 for x.
    int wg  = (int)(blockIdx.x & 7) * 192 + (int)(blockIdx.x >> 3);
    int bt  = wg / 24;
    int rem = wg - bt * 24;
    int ot  = rem / 6;
    int ct  = rem - ot * 6;

    int tid = threadIdx.x;
    int cq  = tid & 1;
    int og  = (tid >> 1) & 7;
    int bq  = tid >> 4;                        // [0, 8)

    int cqg = ct * 2 + cq;                     // [0, 12)
    int c0  = cqg < 11 ? cqg * 4 : 41;         // overlap trick: covers 0..44
    int o0  = ot * 16 + og * 2;
    int b0  = bt * 32 + bq * 4;

    float acc[4][2][4];
#pragma unroll
    for (int bb = 0; bb < 4; ++bb)
#pragma unroll
        for (int oo = 0; oo < 2; ++oo)
#pragma unroll
            for (int cc = 0; cc < 4; ++cc) acc[bb][oo][cc] = 0.0f;

    const float* xp = x + (size_t)b0 * (IC * NSH) + c0;

    if (FOLDED) {
        const float* wp = w + (size_t)c0 * (IC * OC) + o0;
#pragma unroll 4
        for (int i = 0; i < IC; ++i) {
            float xv[4][4];
            float wv[4][2];
#pragma unroll
            for (int bb = 0; bb < 4; ++bb) {
                f4a4 v = *(const f4a4*)(xp + bb * (IC * NSH) + i * NSH);
                xv[bb][0] = v[0]; xv[bb][1] = v[1]; xv[bb][2] = v[2]; xv[bb][3] = v[3];
            }
#pragma unroll
            for (int cc = 0; cc < 4; ++cc) {
                f2a8 v = *(const f2a8*)(wp + cc * (IC * OC) + i * OC);
                wv[cc][0] = v[0]; wv[cc][1] = v[1];
            }
#pragma unroll
            for (int bb = 0; bb < 4; ++bb)
#pragma unroll
                for (int oo = 0; oo < 2; ++oo)
#pragma unroll
                    for (int cc = 0; cc < 4; ++cc)
                        acc[bb][oo][cc] = fmaf(xv[bb][cc], wv[cc][oo], acc[bb][oo][cc]);
        }
#pragma unroll
        for (int bb = 0; bb < 4; ++bb)
#pragma unroll
            for (int oo = 0; oo < 2; ++oo) {
                f4a4 r;
                r[0] = acc[bb][oo][0]; r[1] = acc[bb][oo][1];
                r[2] = acc[bb][oo][2]; r[3] = acc[bb][oo][3];
                *(f4a4*)(out + ((size_t)(b0 + bb) * OC + (o0 + oo)) * NSH + c0) = r;
            }
    } else {
        int l2c[4]; float scl[4];
#pragma unroll
        for (int cc = 0; cc < 4; ++cc) {
            int l = ls[c0 + cc];
            l2c[cc] = l >> 1;
            scl[cc] = sqrtf(PI_F / (2.0f * (float)l + 1.0f));
        }
#pragma unroll 2
        for (int i = 0; i < IC; ++i) {
            float xv[4][4];
            float wv[4][2];
#pragma unroll
            for (int bb = 0; bb < 4; ++bb) {
                f4a4 v = *(const f4a4*)(xp + bb * (IC * NSH) + i * NSH);
                xv[bb][0] = v[0]; xv[bb][1] = v[1]; xv[bb][2] = v[2]; xv[bb][3] = v[3];
            }
#pragma unroll
            for (int cc = 0; cc < 4; ++cc) {
#pragma unroll
                for (int oo = 0; oo < 2; ++oo)
                    wv[cc][oo] = w[((size_t)(o0 + oo) * IC + i) * 5 + l2c[cc]];
            }
#pragma unroll
            for (int bb = 0; bb < 4; ++bb)
#pragma unroll
                for (int oo = 0; oo < 2; ++oo)
#pragma unroll
                    for (int cc = 0; cc < 4; ++cc)
                        acc[bb][oo][cc] = fmaf(xv[bb][cc], wv[cc][oo], acc[bb][oo][cc]);
        }
#pragma unroll
        for (int bb = 0; bb < 4; ++bb)
#pragma unroll
            for (int oo = 0; oo < 2; ++oo) {
                f4a4 r;
                r[0] = acc[bb][oo][0] * scl[0]; r[1] = acc[bb][oo][1] * scl[1];
                r[2] = acc[bb][oo][2] * scl[2]; r[3] = acc[bb][oo][3] * scl[3];
                *(f4a4*)(out + ((size_t)(b0 + bb) * OC + (o0 + oo)) * NSH + c0) = r;
            }
    }
}

extern "C" void kernel_launch(void* const* d_in, const int* in_sizes, int n_in,
                              void* d_out, int out_size, void* d_ws, size_t ws_size,
                              hipStream_t stream) {
    const float* x  = (const float*)d_in[0];
    const float* wt = (const float*)d_in[1];
    const int*   ls = (const int*)d_in[2];
    float* out = (float*)d_out;

    const int nblocks = 64 * 4 * 6;  // 1536

    if (ws_size >= (size_t)WF_FLOATS * sizeof(float)) {
        float* wf = (float*)d_ws;
        fold_kernel<<<(NSH * IC * 16) / 256, 256, 0, stream>>>(wt, ls, wf);
        sph_main<true><<<nblocks, 128, 0, stream>>>(x, wf, ls, out);
    } else {
        sph_main<false><<<nblocks, 128, 0, stream>>>(x, wt, ls, out);
    }
}